// Round 1
// baseline (387.290 us; speedup 1.0000x reference)
//
#include <hip/hip_runtime.h>

#define BB 4096
#define NN 128
#define EPS 1e-5f

// ws layout (floats):
//   [0,128)   bn1 sum    [128,256) bn1 sumsq
//   [256,384) bn2 sum    [384,512) bn2 sumsq
//   [512,640) bn4 sum    [640,768) bn4 sumsq
//   a1: offset 768,       BB*NN*6  floats (12.6 MB)  -- reused as a4 in k3/k4
//   a2: offset 768+BB*NN*6, BB*NN*12 floats (25.2 MB)
#define ST_FLOATS 768
#define A1_OFF ST_FLOATS
#define A1_FLOATS (BB*NN*6)
#define A2_OFF (A1_OFF + A1_FLOATS)

static __device__ __forceinline__ float sigmoidf_(float z){
  return 1.f/(1.f+__expf(-z));
}

__global__ void k_zero(float* __restrict__ st){
  const int t = threadIdx.x;
  for (int i=t;i<ST_FLOATS;i+=256) st[i]=0.f;
}

// fc1 (3->6) + bn1 stats. 1024 blocks x 256 threads, 2 rows/thread, n fixed per thread.
__global__ void k1(const float* __restrict__ x, const float* __restrict__ w1,
                   const float* __restrict__ b1, float* __restrict__ a1,
                   float* __restrict__ st){
  const int tid = blockIdx.x*256 + threadIdx.x;   // 262144 threads
  const int n = tid & 127;
  float W[18], Bv[6];
  #pragma unroll
  for (int i=0;i<18;i++) W[i]=w1[i];
  #pragma unroll
  for (int i=0;i<6;i++) Bv[i]=b1[i];
  float s=0.f, sq=0.f;
  for (int r=tid; r<BB*NN; r+=262144){
    const float* xr = x + (size_t)r*3;
    float x0=xr[0], x1=xr[1], x2=xr[2];
    float* ar = a1 + (size_t)r*6;
    #pragma unroll
    for (int e=0;e<6;e++){
      float a = fmaf(x0,W[e*3+0], fmaf(x1,W[e*3+1], fmaf(x2,W[e*3+2], Bv[e])));
      ar[e]=a; s+=a; sq=fmaf(a,a,sq);
    }
  }
  atomicAdd(&st[n], s);
  atomicAdd(&st[128+n], sq);
}

// bn1+relu + fc2 (6->12) + bn2 stats.
__global__ void k2(const float* __restrict__ a1,
                   const float* __restrict__ g1, const float* __restrict__ bb1,
                   const float* __restrict__ w2, const float* __restrict__ b2,
                   float* __restrict__ a2, float* __restrict__ st){
  const int tid = blockIdx.x*256 + threadIdx.x;
  const int n = tid & 127;
  const float mean = st[n]*(1.f/(BB*6));
  const float var  = st[128+n]*(1.f/(BB*6)) - mean*mean;
  const float rstd = rsqrtf(var+EPS);
  const float sc = g1[n]*rstd, sh = bb1[n]-mean*sc;
  float W[72], Bv[12];
  #pragma unroll
  for (int i=0;i<72;i++) W[i]=w2[i];
  #pragma unroll
  for (int i=0;i<12;i++) Bv[i]=b2[i];
  float s=0.f, sq=0.f;
  for (int r=tid; r<BB*NN; r+=262144){
    const float* ar = a1 + (size_t)r*6;
    float h[6];
    #pragma unroll
    for (int e=0;e<6;e++) h[e]=fmaxf(fmaf(ar[e],sc,sh),0.f);
    float* orow = a2 + (size_t)r*12;
    #pragma unroll
    for (int d=0;d<12;d++){
      float z=Bv[d];
      #pragma unroll
      for (int e=0;e<6;e++) z=fmaf(h[e],W[d*6+e],z);
      orow[d]=z; s+=z; sq=fmaf(z,z,sq);
    }
  }
  atomicAdd(&st[256+n], s);
  atomicAdd(&st[384+n], sq);
}

// bn2+relu + fc3+sigmoid + 4 relation layers (factorized via M = X^T U, 12x12/batch)
// + fc4 + bn4 stats. One block per batch, thread t = row n.
__global__ __launch_bounds__(128) void k3(
  const float* __restrict__ a2,
  const float* __restrict__ g2, const float* __restrict__ bb2,
  const float* __restrict__ w3, const float* __restrict__ b3,
  const float* __restrict__ u1w, const float* __restrict__ u1b,
  const float* __restrict__ ps1, const float* __restrict__ ph1, const float* __restrict__ wr1,
  const float* __restrict__ u2w, const float* __restrict__ u2b,
  const float* __restrict__ ps2, const float* __restrict__ ph2, const float* __restrict__ wr2,
  const float* __restrict__ u3w, const float* __restrict__ u3b,
  const float* __restrict__ ps3, const float* __restrict__ ph3, const float* __restrict__ wr3,
  const float* __restrict__ u4w, const float* __restrict__ u4b,
  const float* __restrict__ ps4, const float* __restrict__ ph4, const float* __restrict__ wr4,
  const float* __restrict__ w4, const float* __restrict__ b4,
  float* __restrict__ a4, float* __restrict__ st)
{
  __shared__ float Xr[128][20];     // cols 0..11 = X row, 12..15 = 0 (pad for k<16 reads)
  __shared__ float Ur[128][12];
  __shared__ float Mp[8][16][12];   // [n-chunk g][k][d] partial M
  __shared__ float Mm[12][12];
  const int t = threadIdx.x;
  const int b = blockIdx.x;

  const float mean = st[256+t]*(1.f/(BB*12));
  const float var  = st[384+t]*(1.f/(BB*12)) - mean*mean;
  const float rstd = rsqrtf(var+EPS);
  const float sc = g2[t]*rstd, sh = bb2[t]-mean*sc;

  const float* arow = a2 + ((size_t)b*128 + t)*12;
  float h[12];
  #pragma unroll
  for (int i=0;i<12;i++) h[i] = fmaxf(fmaf(arow[i], sc, sh), 0.f);

  float X[12];
  #pragma unroll
  for (int d=0; d<12; d++){
    float z = b3[d];
    #pragma unroll
    for (int e=0;e<12;e++) z = fmaf(h[e], w3[d*12+e], z);
    X[d] = sigmoidf_(z);
  }

  const float* UW[4]  = {u1w,u2w,u3w,u4w};
  const float* UBv[4] = {u1b,u2b,u3b,u4b};
  const float cf[4] = {
    wr1[0]*ps1[0]*ph1[0]*(1.f/128.f),
    wr2[0]*ps2[0]*ph2[0]*(1.f/128.f),
    wr3[0]*ps3[0]*ph3[0]*(1.f/128.f),
    wr4[0]*ps4[0]*ph4[0]*(1.f/128.f)
  };

  const int g = t >> 4;      // n-chunk [0,8)
  const int k = t & 15;      // column  [0,16), cols 12..15 read zeros

  #pragma unroll
  for (int l=0;l<4;l++){
    const float* uw = UW[l];
    const float* ub = UBv[l];
    // unary: U = relu(X @ uw^T + ub)  (row-local)
    float U[12];
    #pragma unroll
    for (int d=0;d<12;d++){
      float z = ub[d];
      #pragma unroll
      for (int e=0;e<12;e++) z = fmaf(X[e], uw[d*12+e], z);
      U[d] = fmaxf(z, 0.f);
    }
    float q = 0.f;                              // ||X_i||^2
    #pragma unroll
    for (int e=0;e<12;e++) q = fmaf(X[e], X[e], q);

    // stage X,U rows to LDS
    float4* xr4 = (float4*)&Xr[t][0];
    xr4[0] = make_float4(X[0],X[1],X[2],X[3]);
    xr4[1] = make_float4(X[4],X[5],X[6],X[7]);
    xr4[2] = make_float4(X[8],X[9],X[10],X[11]);
    xr4[3] = make_float4(0.f,0.f,0.f,0.f);
    float4* ur4 = (float4*)&Ur[t][0];
    ur4[0] = make_float4(U[0],U[1],U[2],U[3]);
    ur4[1] = make_float4(U[4],U[5],U[6],U[7]);
    ur4[2] = make_float4(U[8],U[9],U[10],U[11]);
    __syncthreads();

    // partial M[k][d] over n in [16g, 16g+16)
    float mp[12];
    #pragma unroll
    for (int d=0;d<12;d++) mp[d]=0.f;
    #pragma unroll
    for (int i=0;i<16;i++){
      const int n = g*16 + i;
      const float xv = Xr[n][k];
      const float4* un = (const float4*)&Ur[n][0];
      float4 u0=un[0], u1=un[1], u2=un[2];
      mp[0]=fmaf(xv,u0.x,mp[0]); mp[1]=fmaf(xv,u0.y,mp[1]); mp[2]=fmaf(xv,u0.z,mp[2]); mp[3]=fmaf(xv,u0.w,mp[3]);
      mp[4]=fmaf(xv,u1.x,mp[4]); mp[5]=fmaf(xv,u1.y,mp[5]); mp[6]=fmaf(xv,u1.z,mp[6]); mp[7]=fmaf(xv,u1.w,mp[7]);
      mp[8]=fmaf(xv,u2.x,mp[8]); mp[9]=fmaf(xv,u2.y,mp[9]); mp[10]=fmaf(xv,u2.z,mp[10]); mp[11]=fmaf(xv,u2.w,mp[11]);
    }
    float4* mpw = (float4*)&Mp[g][k][0];
    mpw[0]=make_float4(mp[0],mp[1],mp[2],mp[3]);
    mpw[1]=make_float4(mp[4],mp[5],mp[6],mp[7]);
    mpw[2]=make_float4(mp[8],mp[9],mp[10],mp[11]);
    __syncthreads();

    // reduce 8 partials -> Mm
    for (int p=t; p<144; p+=128){
      const int kk=p/12, dd=p-kk*12;
      float ssum = 0.f;
      #pragma unroll
      for (int gg=0;gg<8;gg++) ssum += Mp[gg][kk][dd];
      Mm[kk][dd] = ssum;
    }
    __syncthreads();

    // Y = X @ M  (broadcast reads of Mm), then X' = cf*(Y - q*U)
    float Y[12];
    #pragma unroll
    for (int d=0;d<12;d++) Y[d]=0.f;
    #pragma unroll
    for (int kk=0;kk<12;kk++){
      const float4* mr=(const float4*)&Mm[kk][0];
      float4 m0=mr[0], m1=mr[1], m2=mr[2];
      const float xv = X[kk];
      Y[0]=fmaf(xv,m0.x,Y[0]); Y[1]=fmaf(xv,m0.y,Y[1]); Y[2]=fmaf(xv,m0.z,Y[2]); Y[3]=fmaf(xv,m0.w,Y[3]);
      Y[4]=fmaf(xv,m1.x,Y[4]); Y[5]=fmaf(xv,m1.y,Y[5]); Y[6]=fmaf(xv,m1.z,Y[6]); Y[7]=fmaf(xv,m1.w,Y[7]);
      Y[8]=fmaf(xv,m2.x,Y[8]); Y[9]=fmaf(xv,m2.y,Y[9]); Y[10]=fmaf(xv,m2.z,Y[10]); Y[11]=fmaf(xv,m2.w,Y[11]);
    }
    const float coef = cf[l];
    #pragma unroll
    for (int d=0;d<12;d++) X[d] = coef*(Y[d] - q*U[d]);
    __syncthreads();
  }

  // fc4 (12->6) + bn4 stats
  float s=0.f, sq=0.f;
  float* ar4 = a4 + ((size_t)b*128+t)*6;
  #pragma unroll
  for (int e=0;e<6;e++){
    float z = b4[e];
    #pragma unroll
    for (int d=0;d<12;d++) z = fmaf(X[d], w4[e*12+d], z);
    ar4[e]=z; s+=z; sq=fmaf(z,z,sq);
  }
  atomicAdd(&st[512+t], s);
  atomicAdd(&st[640+t], sq);
}

// bn4+relu + fc5+relu + fc6/fc7 + max over N + fc8 + sigmoid. One block per batch.
__global__ __launch_bounds__(128) void k4(
  const float* __restrict__ a4, const float* __restrict__ g4, const float* __restrict__ bb4,
  const float* __restrict__ w5, const float* __restrict__ b5,
  const float* __restrict__ w6, const float* __restrict__ b6,
  const float* __restrict__ w7, const float* __restrict__ b7,
  const float* __restrict__ w8, const float* __restrict__ b8,
  const float* __restrict__ st, float* __restrict__ out)
{
  __shared__ float red[128][4];
  const int t=threadIdx.x, b=blockIdx.x;
  const float mean = st[512+t]*(1.f/(BB*6));
  const float var  = st[640+t]*(1.f/(BB*6)) - mean*mean;
  const float rstd = rsqrtf(var+EPS);
  const float sc = g4[t]*rstd, sh = bb4[t]-mean*sc;
  const float* ar = a4 + ((size_t)b*128+t)*6;
  float h[6];
  #pragma unroll
  for (int e=0;e<6;e++) h[e] = fmaxf(fmaf(ar[e],sc,sh),0.f);
  float h5[3];
  #pragma unroll
  for (int f=0;f<3;f++){
    float z=b5[f];
    #pragma unroll
    for (int e=0;e<6;e++) z=fmaf(h[e],w5[f*6+e],z);
    h5[f]=fmaxf(z,0.f);
  }
  float c0=b6[0];
  #pragma unroll
  for (int f=0;f<3;f++) c0=fmaf(h5[f],w6[f],c0);
  float g0=b7[0], g1=b7[1];
  #pragma unroll
  for (int f=0;f<3;f++){ g0=fmaf(h5[f],w7[f],g0); g1=fmaf(h5[f],w7[3+f],g1); }
  red[t][0]=c0; red[t][1]=g0; red[t][2]=g1;
  __syncthreads();
  for (int sft=64; sft>0; sft>>=1){
    if (t<sft){
      red[t][0]=fmaxf(red[t][0],red[t+sft][0]);
      red[t][1]=fmaxf(red[t][1],red[t+sft][1]);
      red[t][2]=fmaxf(red[t][2],red[t+sft][2]);
    }
    __syncthreads();
  }
  if (t==0){
    float z=b8[0]+red[0][0]*w8[0]+red[0][1]*w8[1]+red[0][2]*w8[2];
    out[b]=sigmoidf_(z);
  }
}

extern "C" void kernel_launch(void* const* d_in, const int* in_sizes, int n_in,
                              void* d_out, int out_size, void* d_ws, size_t ws_size,
                              hipStream_t stream){
  const float* x   = (const float*)d_in[0];
  const float* f1w = (const float*)d_in[1];
  const float* f1b = (const float*)d_in[2];
  const float* g1  = (const float*)d_in[3];
  const float* bb1 = (const float*)d_in[4];
  const float* f2w = (const float*)d_in[5];
  const float* f2b = (const float*)d_in[6];
  const float* g2  = (const float*)d_in[7];
  const float* bb2 = (const float*)d_in[8];
  const float* f3w = (const float*)d_in[9];
  const float* f3b = (const float*)d_in[10];
  const float* u1w = (const float*)d_in[11];
  const float* u1b = (const float*)d_in[12];
  const float* ps1 = (const float*)d_in[13];
  const float* ph1 = (const float*)d_in[14];
  const float* wr1 = (const float*)d_in[15];
  const float* u2w = (const float*)d_in[16];
  const float* u2b = (const float*)d_in[17];
  const float* ps2 = (const float*)d_in[18];
  const float* ph2 = (const float*)d_in[19];
  const float* wr2 = (const float*)d_in[20];
  const float* u3w = (const float*)d_in[21];
  const float* u3b = (const float*)d_in[22];
  const float* ps3 = (const float*)d_in[23];
  const float* ph3 = (const float*)d_in[24];
  const float* wr3 = (const float*)d_in[25];
  const float* u4w = (const float*)d_in[26];
  const float* u4b = (const float*)d_in[27];
  const float* ps4 = (const float*)d_in[28];
  const float* ph4 = (const float*)d_in[29];
  const float* wr4 = (const float*)d_in[30];
  const float* f4w = (const float*)d_in[31];
  const float* f4b = (const float*)d_in[32];
  const float* g4  = (const float*)d_in[33];
  const float* bb4 = (const float*)d_in[34];
  const float* f5w = (const float*)d_in[35];
  const float* f5b = (const float*)d_in[36];
  const float* f6w = (const float*)d_in[37];
  const float* f6b = (const float*)d_in[38];
  const float* f7w = (const float*)d_in[39];
  const float* f7b = (const float*)d_in[40];
  const float* f8w = (const float*)d_in[41];
  const float* f8b = (const float*)d_in[42];

  float* wsf = (float*)d_ws;
  float* st  = wsf;
  float* a1  = wsf + A1_OFF;
  float* a2  = wsf + A2_OFF;
  float* a4  = a1;                 // a1 dead after k2; reuse as a4
  float* out = (float*)d_out;

  k_zero<<<dim3(1), dim3(256), 0, stream>>>(st);
  k1<<<dim3(1024), dim3(256), 0, stream>>>(x, f1w, f1b, a1, st);
  k2<<<dim3(1024), dim3(256), 0, stream>>>(a1, g1, bb1, f2w, f2b, a2, st);
  k3<<<dim3(4096), dim3(128), 0, stream>>>(a2, g2, bb2, f3w, f3b,
      u1w,u1b,ps1,ph1,wr1, u2w,u2b,ps2,ph2,wr2,
      u3w,u3b,ps3,ph3,wr3, u4w,u4b,ps4,ph4,wr4,
      f4w, f4b, a4, st);
  k4<<<dim3(4096), dim3(128), 0, stream>>>(a4, g4, bb4, f5w, f5b,
      f6w, f6b, f7w, f7b, f8w, f8b, st, out);
}

// Round 2
// 272.800 us; speedup vs baseline: 1.4197x; 1.4197x over previous
//
#include <hip/hip_runtime.h>

#define BB 4096
#define NN 128
#define EPS 1e-5f

// ws layout (floats):
//   [0,128)   bn1 sum    [128,256) bn1 sumsq
//   [256,384) bn2 sum    [384,512) bn2 sumsq
//   [512,640) bn4 sum    [640,768) bn4 sumsq
//   a1: offset 768,  BB*NN*6 floats  -- reused as a4
//   a2: offset 768+BB*NN*6, BB*NN*12 floats
#define ST_FLOATS 768
#define A1_OFF ST_FLOATS
#define A1_FLOATS (BB*NN*6)
#define A2_OFF (A1_OFF + A1_FLOATS)

static __device__ __forceinline__ float sigmoidf_(float z){
  return 1.f/(1.f+__expf(-z));
}

// fc1 (3->6) + bn1 stats. 512x256, 4 rows/thread, stride 131072 keeps n fixed.
__global__ __launch_bounds__(256) void k1(const float* __restrict__ x, const float* __restrict__ w1,
                   const float* __restrict__ b1, float* __restrict__ a1,
                   float* __restrict__ st){
  const int tid = blockIdx.x*256 + threadIdx.x;   // 131072 threads
  const int n = tid & 127;
  float W[18], Bv[6];
  #pragma unroll
  for (int i=0;i<18;i++) W[i]=w1[i];
  #pragma unroll
  for (int i=0;i<6;i++) Bv[i]=b1[i];
  float s=0.f, sq=0.f;
  #pragma unroll
  for (int kk=0;kk<4;kk++){
    const int r = tid + kk*131072;
    const float* xr = x + (size_t)r*3;
    float x0=xr[0], x1=xr[1], x2=xr[2];
    float a[6];
    #pragma unroll
    for (int e=0;e<6;e++){
      a[e] = fmaf(x0,W[e*3+0], fmaf(x1,W[e*3+1], fmaf(x2,W[e*3+2], Bv[e])));
      s+=a[e]; sq=fmaf(a[e],a[e],sq);
    }
    float2* ar = (float2*)(a1 + (size_t)r*6);
    ar[0]=make_float2(a[0],a[1]); ar[1]=make_float2(a[2],a[3]); ar[2]=make_float2(a[4],a[5]);
  }
  atomicAdd(&st[n], s);
  atomicAdd(&st[128+n], sq);
}

// bn1+relu + fc2 (6->12) + bn2 stats. 512x256, 4 rows/thread.
__global__ __launch_bounds__(256) void k2(const float* __restrict__ a1,
                   const float* __restrict__ g1, const float* __restrict__ bb1,
                   const float* __restrict__ w2, const float* __restrict__ b2,
                   float* __restrict__ a2, float* __restrict__ st){
  const int tid = blockIdx.x*256 + threadIdx.x;
  const int n = tid & 127;
  const float mean = st[n]*(1.f/(BB*6));
  const float var  = st[128+n]*(1.f/(BB*6)) - mean*mean;
  const float rstd = rsqrtf(var+EPS);
  const float sc = g1[n]*rstd, sh = bb1[n]-mean*sc;
  float W[72], Bv[12];
  #pragma unroll
  for (int i=0;i<72;i++) W[i]=w2[i];
  #pragma unroll
  for (int i=0;i<12;i++) Bv[i]=b2[i];
  float s=0.f, sq=0.f;
  #pragma unroll
  for (int kk=0;kk<4;kk++){
    const int r = tid + kk*131072;
    const float2* ar = (const float2*)(a1 + (size_t)r*6);
    float2 p0=ar[0], p1=ar[1], p2=ar[2];
    float h[6] = {p0.x,p0.y,p1.x,p1.y,p2.x,p2.y};
    #pragma unroll
    for (int e=0;e<6;e++) h[e]=fmaxf(fmaf(h[e],sc,sh),0.f);
    float z[12];
    #pragma unroll
    for (int d=0;d<12;d++){
      float zz=Bv[d];
      #pragma unroll
      for (int e=0;e<6;e++) zz=fmaf(h[e],W[d*6+e],zz);
      z[d]=zz; s+=zz; sq=fmaf(zz,zz,sq);
    }
    float4* orow = (float4*)(a2 + (size_t)r*12);
    orow[0]=make_float4(z[0],z[1],z[2],z[3]);
    orow[1]=make_float4(z[4],z[5],z[6],z[7]);
    orow[2]=make_float4(z[8],z[9],z[10],z[11]);
  }
  atomicAdd(&st[256+n], s);
  atomicAdd(&st[384+n], sq);
}

// bn2+relu + fc3+sigmoid + 4 relation layers + fc4 + bn4 stats.
// ONE WAVE PER BATCH (2 rows/lane), 4 waves/block, per-wave private LDS,
// zero barriers in the layer loop (wave-coherent LDS + shfl reductions).
#define WREG 3264   // floats per wave region: Xs 1536 + Us 1536 + Ms 192
__global__ __launch_bounds__(256) void k3(
  const float* __restrict__ a2,
  const float* __restrict__ g2, const float* __restrict__ bb2,
  const float* __restrict__ w3, const float* __restrict__ b3,
  const float* __restrict__ u1w, const float* __restrict__ u1b,
  const float* __restrict__ ps1, const float* __restrict__ ph1, const float* __restrict__ wr1,
  const float* __restrict__ u2w, const float* __restrict__ u2b,
  const float* __restrict__ ps2, const float* __restrict__ ph2, const float* __restrict__ wr2,
  const float* __restrict__ u3w, const float* __restrict__ u3b,
  const float* __restrict__ ps3, const float* __restrict__ ph3, const float* __restrict__ wr3,
  const float* __restrict__ u4w, const float* __restrict__ u4b,
  const float* __restrict__ ps4, const float* __restrict__ ph4, const float* __restrict__ wr4,
  const float* __restrict__ w4, const float* __restrict__ b4,
  float* __restrict__ a4, float* __restrict__ st)
{
  __shared__ float lds[4][WREG];
  const int wave = threadIdx.x >> 6;
  const int lane = threadIdx.x & 63;
  const int b = blockIdx.x*4 + wave;
  float* Xs = &lds[wave][0];
  float* Us = &lds[wave][1536];
  float* Ms = &lds[wave][3072];
  const int r0 = lane*2, r1 = r0+1;

  const float inv = 1.f/(BB*12);
  const float mean0 = st[256+r0]*inv;
  const float var0  = st[384+r0]*inv - mean0*mean0;
  const float sc0 = g2[r0]*rsqrtf(var0+EPS), sh0 = bb2[r0]-mean0*sc0;
  const float mean1 = st[256+r1]*inv;
  const float var1  = st[384+r1]*inv - mean1*mean1;
  const float sc1 = g2[r1]*rsqrtf(var1+EPS), sh1 = bb2[r1]-mean1*sc1;

  // load two a2 rows (24 consecutive floats)
  const float4* arow = (const float4*)(a2 + ((size_t)b*128 + r0)*12);
  float4 v[6];
  #pragma unroll
  for (int i=0;i<6;i++) v[i]=arow[i];
  const float* av = (const float*)v;
  float h0[12], h1[12];
  #pragma unroll
  for (int i=0;i<12;i++){
    h0[i]=fmaxf(fmaf(av[i],   sc0, sh0), 0.f);
    h1[i]=fmaxf(fmaf(av[12+i],sc1, sh1), 0.f);
  }

  float X0[12], X1[12];
  #pragma unroll
  for (int d=0; d<12; d++){
    float z0=b3[d], z1=b3[d];
    #pragma unroll
    for (int e=0;e<12;e++){ z0=fmaf(h0[e],w3[d*12+e],z0); z1=fmaf(h1[e],w3[d*12+e],z1); }
    X0[d]=sigmoidf_(z0); X1[d]=sigmoidf_(z1);
  }

  const float* UW[4]  = {u1w,u2w,u3w,u4w};
  const float* UBv[4] = {u1b,u2b,u3b,u4b};
  const float cf[4] = {
    wr1[0]*ps1[0]*ph1[0]*(1.f/128.f),
    wr2[0]*ps2[0]*ph2[0]*(1.f/128.f),
    wr3[0]*ps3[0]*ph3[0]*(1.f/128.f),
    wr4[0]*ps4[0]*ph4[0]*(1.f/128.f)
  };

  const int g = lane>>4;
  int kc = lane & 15; if (kc>11) kc=11;

  #pragma unroll
  for (int l=0;l<4;l++){
    const float* uw = UW[l];
    const float* ub = UBv[l];
    float U0[12], U1[12];
    #pragma unroll
    for (int d=0;d<12;d++){
      float z0=ub[d], z1=ub[d];
      #pragma unroll
      for (int e=0;e<12;e++){ z0=fmaf(X0[e],uw[d*12+e],z0); z1=fmaf(X1[e],uw[d*12+e],z1); }
      U0[d]=fmaxf(z0,0.f); U1[d]=fmaxf(z1,0.f);
    }
    float q0=0.f, q1=0.f;
    #pragma unroll
    for (int e=0;e<12;e++){ q0=fmaf(X0[e],X0[e],q0); q1=fmaf(X1[e],X1[e],q1); }

    // stage both rows (24 consecutive floats each array)
    float4* xw = (float4*)(Xs + (size_t)r0*12);
    xw[0]=make_float4(X0[0],X0[1],X0[2],X0[3]);
    xw[1]=make_float4(X0[4],X0[5],X0[6],X0[7]);
    xw[2]=make_float4(X0[8],X0[9],X0[10],X0[11]);
    xw[3]=make_float4(X1[0],X1[1],X1[2],X1[3]);
    xw[4]=make_float4(X1[4],X1[5],X1[6],X1[7]);
    xw[5]=make_float4(X1[8],X1[9],X1[10],X1[11]);
    float4* uwr = (float4*)(Us + (size_t)r0*12);
    uwr[0]=make_float4(U0[0],U0[1],U0[2],U0[3]);
    uwr[1]=make_float4(U0[4],U0[5],U0[6],U0[7]);
    uwr[2]=make_float4(U0[8],U0[9],U0[10],U0[11]);
    uwr[3]=make_float4(U1[0],U1[1],U1[2],U1[3]);
    uwr[4]=make_float4(U1[4],U1[5],U1[6],U1[7]);
    uwr[5]=make_float4(U1[8],U1[9],U1[10],U1[11]);
    // wave-coherent LDS: compiler's lgkmcnt waits order write->read, no barrier.

    // partial M[kc][d] over 32 rows; rotation (i+g)&31 de-conflicts banks across g
    float mp[12];
    #pragma unroll
    for (int d=0;d<12;d++) mp[d]=0.f;
    #pragma unroll
    for (int i=0;i<32;i++){
      const int n = g*32 + ((i+g)&31);
      const float xv = Xs[n*12 + kc];
      const float4* up = (const float4*)(Us + n*12);
      float4 u0=up[0], u1=up[1], u2=up[2];
      mp[0]=fmaf(xv,u0.x,mp[0]); mp[1]=fmaf(xv,u0.y,mp[1]); mp[2]=fmaf(xv,u0.z,mp[2]); mp[3]=fmaf(xv,u0.w,mp[3]);
      mp[4]=fmaf(xv,u1.x,mp[4]); mp[5]=fmaf(xv,u1.y,mp[5]); mp[6]=fmaf(xv,u1.z,mp[6]); mp[7]=fmaf(xv,u1.w,mp[7]);
      mp[8]=fmaf(xv,u2.x,mp[8]); mp[9]=fmaf(xv,u2.y,mp[9]); mp[10]=fmaf(xv,u2.z,mp[10]); mp[11]=fmaf(xv,u2.w,mp[11]);
    }
    // reduce over the 4 g-chunks (lanes ^16, ^32) in-register
    #pragma unroll
    for (int d=0;d<12;d++) mp[d] += __shfl_xor(mp[d], 16, 64);
    #pragma unroll
    for (int d=0;d<12;d++) mp[d] += __shfl_xor(mp[d], 32, 64);
    if (lane < 12){
      float4* mw = (float4*)(Ms + (size_t)lane*12);
      mw[0]=make_float4(mp[0],mp[1],mp[2],mp[3]);
      mw[1]=make_float4(mp[4],mp[5],mp[6],mp[7]);
      mw[2]=make_float4(mp[8],mp[9],mp[10],mp[11]);
    }

    // Y = X @ M  (all-lane broadcast reads of Ms)
    float Y0[12], Y1[12];
    #pragma unroll
    for (int d=0;d<12;d++){ Y0[d]=0.f; Y1[d]=0.f; }
    #pragma unroll
    for (int kk=0;kk<12;kk++){
      const float4* mr=(const float4*)(Ms + (size_t)kk*12);
      float4 m0=mr[0], m1=mr[1], m2=mr[2];
      const float xa = X0[kk], xb = X1[kk];
      Y0[0]=fmaf(xa,m0.x,Y0[0]); Y0[1]=fmaf(xa,m0.y,Y0[1]); Y0[2]=fmaf(xa,m0.z,Y0[2]); Y0[3]=fmaf(xa,m0.w,Y0[3]);
      Y0[4]=fmaf(xa,m1.x,Y0[4]); Y0[5]=fmaf(xa,m1.y,Y0[5]); Y0[6]=fmaf(xa,m1.z,Y0[6]); Y0[7]=fmaf(xa,m1.w,Y0[7]);
      Y0[8]=fmaf(xa,m2.x,Y0[8]); Y0[9]=fmaf(xa,m2.y,Y0[9]); Y0[10]=fmaf(xa,m2.z,Y0[10]); Y0[11]=fmaf(xa,m2.w,Y0[11]);
      Y1[0]=fmaf(xb,m0.x,Y1[0]); Y1[1]=fmaf(xb,m0.y,Y1[1]); Y1[2]=fmaf(xb,m0.z,Y1[2]); Y1[3]=fmaf(xb,m0.w,Y1[3]);
      Y1[4]=fmaf(xb,m1.x,Y1[4]); Y1[5]=fmaf(xb,m1.y,Y1[5]); Y1[6]=fmaf(xb,m1.z,Y1[6]); Y1[7]=fmaf(xb,m1.w,Y1[7]);
      Y1[8]=fmaf(xb,m2.x,Y1[8]); Y1[9]=fmaf(xb,m2.y,Y1[9]); Y1[10]=fmaf(xb,m2.z,Y1[10]); Y1[11]=fmaf(xb,m2.w,Y1[11]);
    }
    const float coef = cf[l];
    #pragma unroll
    for (int d=0;d<12;d++){
      X0[d] = coef*(Y0[d] - q0*U0[d]);
      X1[d] = coef*(Y1[d] - q1*U1[d]);
    }
  }

  // fc4 (12->6), write a4, bn4 stats via one block-level reduction
  float z0[6], z1[6];
  float s0=0.f,sq0=0.f,s1=0.f,sq1=0.f;
  #pragma unroll
  for (int e=0;e<6;e++){
    float a0=b4[e], a1v=b4[e];
    #pragma unroll
    for (int d=0;d<12;d++){ a0=fmaf(X0[d],w4[e*12+d],a0); a1v=fmaf(X1[d],w4[e*12+d],a1v); }
    z0[e]=a0; z1[e]=a1v;
    s0+=a0; sq0=fmaf(a0,a0,sq0); s1+=a1v; sq1=fmaf(a1v,a1v,sq1);
  }
  float4* aw = (float4*)(a4 + ((size_t)b*128 + r0)*6);
  aw[0]=make_float4(z0[0],z0[1],z0[2],z0[3]);
  aw[1]=make_float4(z0[4],z0[5],z1[0],z1[1]);
  aw[2]=make_float4(z1[2],z1[3],z1[4],z1[5]);

  // per-wave stats into own region, one barrier, cross-wave sum, 1 atomic/thread
  lds[wave][r0]=s0; lds[wave][r1]=s1;
  lds[wave][128+r0]=sq0; lds[wave][128+r1]=sq1;
  __syncthreads();
  const int t = threadIdx.x;
  if (t < 128){
    float tot = lds[0][t]+lds[1][t]+lds[2][t]+lds[3][t];
    atomicAdd(&st[512+t], tot);
  } else {
    const int tt = t-128;
    float tot = lds[0][128+tt]+lds[1][128+tt]+lds[2][128+tt]+lds[3][128+tt];
    atomicAdd(&st[640+tt], tot);
  }
}

// bn4+relu + fc5+relu + fc6/fc7 + max over N + fc8 + sigmoid.
// One wave per batch, 2 rows/lane, shuffle max, no LDS/barriers.
__global__ __launch_bounds__(256) void k4(
  const float* __restrict__ a4, const float* __restrict__ g4, const float* __restrict__ bb4,
  const float* __restrict__ w5, const float* __restrict__ b5,
  const float* __restrict__ w6, const float* __restrict__ b6,
  const float* __restrict__ w7, const float* __restrict__ b7,
  const float* __restrict__ w8, const float* __restrict__ b8,
  const float* __restrict__ st, float* __restrict__ out)
{
  const int wave = threadIdx.x>>6, lane = threadIdx.x&63;
  const int b = blockIdx.x*4 + wave;
  const int r0 = lane*2, r1 = r0+1;
  const float inv = 1.f/(BB*6);
  const float mean0 = st[512+r0]*inv;
  const float var0  = st[640+r0]*inv - mean0*mean0;
  const float sc0 = g4[r0]*rsqrtf(var0+EPS), sh0 = bb4[r0]-mean0*sc0;
  const float mean1 = st[512+r1]*inv;
  const float var1  = st[640+r1]*inv - mean1*mean1;
  const float sc1 = g4[r1]*rsqrtf(var1+EPS), sh1 = bb4[r1]-mean1*sc1;

  const float4* ar = (const float4*)(a4 + ((size_t)b*128 + r0)*6);
  float4 p0=ar[0], p1=ar[1], p2=ar[2];
  float h0[6] = {p0.x,p0.y,p0.z,p0.w,p1.x,p1.y};
  float h1[6] = {p1.z,p1.w,p2.x,p2.y,p2.z,p2.w};
  #pragma unroll
  for (int e=0;e<6;e++){
    h0[e]=fmaxf(fmaf(h0[e],sc0,sh0),0.f);
    h1[e]=fmaxf(fmaf(h1[e],sc1,sh1),0.f);
  }
  float m[3];
  {
    float h5a[3], h5b[3];
    #pragma unroll
    for (int f=0;f<3;f++){
      float za=b5[f], zb=b5[f];
      #pragma unroll
      for (int e=0;e<6;e++){ za=fmaf(h0[e],w5[f*6+e],za); zb=fmaf(h1[e],w5[f*6+e],zb); }
      h5a[f]=fmaxf(za,0.f); h5b[f]=fmaxf(zb,0.f);
    }
    float ca=b6[0], cb=b6[0];
    float g0a=b7[0], g0b=b7[0], g1a=b7[1], g1b=b7[1];
    #pragma unroll
    for (int f=0;f<3;f++){
      ca=fmaf(h5a[f],w6[f],ca);   cb=fmaf(h5b[f],w6[f],cb);
      g0a=fmaf(h5a[f],w7[f],g0a); g0b=fmaf(h5b[f],w7[f],g0b);
      g1a=fmaf(h5a[f],w7[3+f],g1a); g1b=fmaf(h5b[f],w7[3+f],g1b);
    }
    m[0]=fmaxf(ca,cb); m[1]=fmaxf(g0a,g0b); m[2]=fmaxf(g1a,g1b);
  }
  #pragma unroll
  for (int off=32; off>0; off>>=1){
    m[0]=fmaxf(m[0], __shfl_xor(m[0],off,64));
    m[1]=fmaxf(m[1], __shfl_xor(m[1],off,64));
    m[2]=fmaxf(m[2], __shfl_xor(m[2],off,64));
  }
  if (lane==0){
    float z = b8[0] + m[0]*w8[0] + m[1]*w8[1] + m[2]*w8[2];
    out[b]=sigmoidf_(z);
  }
}

extern "C" void kernel_launch(void* const* d_in, const int* in_sizes, int n_in,
                              void* d_out, int out_size, void* d_ws, size_t ws_size,
                              hipStream_t stream){
  const float* x   = (const float*)d_in[0];
  const float* f1w = (const float*)d_in[1];
  const float* f1b = (const float*)d_in[2];
  const float* g1  = (const float*)d_in[3];
  const float* bb1 = (const float*)d_in[4];
  const float* f2w = (const float*)d_in[5];
  const float* f2b = (const float*)d_in[6];
  const float* g2  = (const float*)d_in[7];
  const float* bb2 = (const float*)d_in[8];
  const float* f3w = (const float*)d_in[9];
  const float* f3b = (const float*)d_in[10];
  const float* u1w = (const float*)d_in[11];
  const float* u1b = (const float*)d_in[12];
  const float* ps1 = (const float*)d_in[13];
  const float* ph1 = (const float*)d_in[14];
  const float* wr1 = (const float*)d_in[15];
  const float* u2w = (const float*)d_in[16];
  const float* u2b = (const float*)d_in[17];
  const float* ps2 = (const float*)d_in[18];
  const float* ph2 = (const float*)d_in[19];
  const float* wr2 = (const float*)d_in[20];
  const float* u3w = (const float*)d_in[21];
  const float* u3b = (const float*)d_in[22];
  const float* ps3 = (const float*)d_in[23];
  const float* ph3 = (const float*)d_in[24];
  const float* wr3 = (const float*)d_in[25];
  const float* u4w = (const float*)d_in[26];
  const float* u4b = (const float*)d_in[27];
  const float* ps4 = (const float*)d_in[28];
  const float* ph4 = (const float*)d_in[29];
  const float* wr4 = (const float*)d_in[30];
  const float* f4w = (const float*)d_in[31];
  const float* f4b = (const float*)d_in[32];
  const float* g4  = (const float*)d_in[33];
  const float* bb4 = (const float*)d_in[34];
  const float* f5w = (const float*)d_in[35];
  const float* f5b = (const float*)d_in[36];
  const float* f6w = (const float*)d_in[37];
  const float* f6b = (const float*)d_in[38];
  const float* f7w = (const float*)d_in[39];
  const float* f7b = (const float*)d_in[40];
  const float* f8w = (const float*)d_in[41];
  const float* f8b = (const float*)d_in[42];

  float* wsf = (float*)d_ws;
  float* st  = wsf;
  float* a1  = wsf + A1_OFF;
  float* a2  = wsf + A2_OFF;
  float* a4  = a1;                 // a1 dead after k2; reuse as a4
  float* out = (float*)d_out;

  hipMemsetAsync(st, 0, ST_FLOATS*sizeof(float), stream);
  k1<<<dim3(512), dim3(256), 0, stream>>>(x, f1w, f1b, a1, st);
  k2<<<dim3(512), dim3(256), 0, stream>>>(a1, g1, bb1, f2w, f2b, a2, st);
  k3<<<dim3(1024), dim3(256), 0, stream>>>(a2, g2, bb2, f3w, f3b,
      u1w,u1b,ps1,ph1,wr1, u2w,u2b,ps2,ph2,wr2,
      u3w,u3b,ps3,ph3,wr3, u4w,u4b,ps4,ph4,wr4,
      f4w, f4b, a4, st);
  k4<<<dim3(1024), dim3(256), 0, stream>>>(a4, g4, bb4, f5w, f5b,
      f6w, f6b, f7w, f7b, f8w, f8b, st, out);
}

// Round 3
// 220.352 us; speedup vs baseline: 1.7576x; 1.2380x over previous
//
#include <hip/hip_runtime.h>
#include <hip/hip_fp16.h>

#define BB 4096
#define NN 128
#define EPS 1e-5f

// ws layout (floats):
//   [0,128)    bn1 sum    [128,256)  bn1 sumsq
//   [256,384)  bn2 sum    [384,512)  bn2 sumsq
//   [512,2560) bn4 stats: 8 shadow copies x (128 sum + 128 sumsq)
//   a4: offset 2560, BB*NN*6 floats (12.6 MB)
#define ST_FLOATS 2560
#define A4_OFF ST_FLOATS

static __device__ __forceinline__ float sigmoidf_(float z){
  return 1.f/(1.f+__expf(-z));
}

// fc1 (3->6) stats only. 128 blocks x 256 threads, 16 rows/thread, n fixed.
__global__ __launch_bounds__(256) void k1(const float* __restrict__ x, const float* __restrict__ w1,
                   const float* __restrict__ b1, float* __restrict__ st){
  __shared__ float bl[512];
  const int t = threadIdx.x;
  const int tid = blockIdx.x*256 + t;      // 32768 threads
  const int n = tid & 127;
  float W[18], Bv[6];
  #pragma unroll
  for (int i=0;i<18;i++) W[i]=w1[i];
  #pragma unroll
  for (int i=0;i<6;i++) Bv[i]=b1[i];
  float s=0.f, sq=0.f;
  #pragma unroll
  for (int kk=0;kk<16;kk++){
    const int r = tid + kk*32768;
    const float* xr = x + (size_t)r*3;
    float x0=xr[0], x1=xr[1], x2=xr[2];
    #pragma unroll
    for (int e=0;e<6;e++){
      float a = fmaf(x0,W[e*3+0], fmaf(x1,W[e*3+1], fmaf(x2,W[e*3+2], Bv[e])));
      s+=a; sq=fmaf(a,a,sq);
    }
  }
  bl[t]=s; bl[256+t]=sq;
  __syncthreads();
  if (t<128){
    atomicAdd(&st[t], bl[t]+bl[t+128]);
  } else {
    const int tt=t-128;
    atomicAdd(&st[128+tt], bl[256+tt]+bl[256+tt+128]);
  }
}

// recompute fc1+bn1+relu, fc2 (6->12) stats only. Same shape as k1.
__global__ __launch_bounds__(256) void k2(const float* __restrict__ x,
                   const float* __restrict__ w1, const float* __restrict__ b1,
                   const float* __restrict__ g1, const float* __restrict__ bb1,
                   const float* __restrict__ w2, const float* __restrict__ b2,
                   float* __restrict__ st){
  __shared__ float bl[512];
  const int t = threadIdx.x;
  const int tid = blockIdx.x*256 + t;
  const int n = tid & 127;
  const float mean = st[n]*(1.f/(BB*6));
  const float var  = st[128+n]*(1.f/(BB*6)) - mean*mean;
  const float sc = g1[n]*rsqrtf(var+EPS), sh = bb1[n]-mean*sc;
  float W1[18], B1v[6], W2[72], B2v[12];
  #pragma unroll
  for (int i=0;i<18;i++) W1[i]=w1[i];
  #pragma unroll
  for (int i=0;i<6;i++) B1v[i]=b1[i];
  #pragma unroll
  for (int i=0;i<72;i++) W2[i]=w2[i];
  #pragma unroll
  for (int i=0;i<12;i++) B2v[i]=b2[i];
  float s=0.f, sq=0.f;
  #pragma unroll
  for (int kk=0;kk<16;kk++){
    const int r = tid + kk*32768;
    const float* xr = x + (size_t)r*3;
    float x0=xr[0], x1=xr[1], x2=xr[2];
    float h[6];
    #pragma unroll
    for (int e=0;e<6;e++){
      float a = fmaf(x0,W1[e*3+0], fmaf(x1,W1[e*3+1], fmaf(x2,W1[e*3+2], B1v[e])));
      h[e]=fmaxf(fmaf(a,sc,sh),0.f);
    }
    #pragma unroll
    for (int d=0;d<12;d++){
      float z=B2v[d];
      #pragma unroll
      for (int e=0;e<6;e++) z=fmaf(h[e],W2[d*6+e],z);
      s+=z; sq=fmaf(z,z,sq);
    }
  }
  bl[t]=s; bl[256+t]=sq;
  __syncthreads();
  if (t<128){
    atomicAdd(&st[256+t], bl[t]+bl[t+128]);
  } else {
    const int tt=t-128;
    atomicAdd(&st[384+tt], bl[256+tt]+bl[256+tt+128]);
  }
}

// head recompute (fc1..bn2..fc3 sigmoid) + 4 relation layers + fc4 + bn4 stats.
// One wave per batch, 2 rows/lane, per-wave LDS: Us 6144B f32 + Xs 3072B f16 = 9216B.
// Block 4 waves = 36864B -> 4 blocks/CU; M broadcast via v_readlane (no Ms in LDS).
__global__ __launch_bounds__(256,4) void k3(
  const float* __restrict__ x,
  const float* __restrict__ w1, const float* __restrict__ b1,
  const float* __restrict__ g1, const float* __restrict__ bb1,
  const float* __restrict__ w2, const float* __restrict__ b2,
  const float* __restrict__ g2, const float* __restrict__ bb2,
  const float* __restrict__ w3, const float* __restrict__ b3,
  const float* __restrict__ u1w, const float* __restrict__ u1b,
  const float* __restrict__ ps1, const float* __restrict__ ph1, const float* __restrict__ wr1,
  const float* __restrict__ u2w, const float* __restrict__ u2b,
  const float* __restrict__ ps2, const float* __restrict__ ph2, const float* __restrict__ wr2,
  const float* __restrict__ u3w, const float* __restrict__ u3b,
  const float* __restrict__ ps3, const float* __restrict__ ph3, const float* __restrict__ wr3,
  const float* __restrict__ u4w, const float* __restrict__ u4b,
  const float* __restrict__ ps4, const float* __restrict__ ph4, const float* __restrict__ wr4,
  const float* __restrict__ w4, const float* __restrict__ b4,
  float* __restrict__ a4, float* __restrict__ st)
{
  __shared__ float lds[4][2304];
  const int wave = threadIdx.x >> 6;
  const int lane = threadIdx.x & 63;
  const int b = blockIdx.x*4 + wave;
  float* Us = &lds[wave][0];
  __half* Xs = (__half*)&lds[wave][1536];
  const int r0 = lane*2, r1 = r0+1;

  // ---- head: fc1 + bn1 + relu + fc2 + bn2 + relu + fc3 + sigmoid ----
  const float inv1 = 1.f/(BB*6);
  const float m10 = st[r0]*inv1, v10 = st[128+r0]*inv1 - m10*m10;
  const float sA0 = g1[r0]*rsqrtf(v10+EPS), hA0 = bb1[r0]-m10*sA0;
  const float m11 = st[r1]*inv1, v11 = st[128+r1]*inv1 - m11*m11;
  const float sA1 = g1[r1]*rsqrtf(v11+EPS), hA1 = bb1[r1]-m11*sA1;
  const float inv2 = 1.f/(BB*12);
  const float m20 = st[256+r0]*inv2, v20 = st[384+r0]*inv2 - m20*m20;
  const float sB0 = g2[r0]*rsqrtf(v20+EPS), hB0 = bb2[r0]-m20*sB0;
  const float m21 = st[256+r1]*inv2, v21 = st[384+r1]*inv2 - m21*m21;
  const float sB1 = g2[r1]*rsqrtf(v21+EPS), hB1 = bb2[r1]-m21*sB1;

  // two x rows = 12 consecutive floats, 8B aligned
  const float2* xr = (const float2*)(x + ((size_t)b*128 + r0)*3);
  float2 q0v=xr[0], q1v=xr[1], q2v=xr[2], q3v=xr[3], q4v=xr[4], q5v=xr[5];
  const float xa0=q0v.x, xa1=q0v.y, xa2=q1v.x;
  const float xb0=q1v.y, xb1=q2v.x, xb2=q2v.y;
  // wait: rows are 3 floats each: row0 = {q0v.x,q0v.y,q1v.x}, row1 = {q1v.y,q2v.x,q2v.y}
  // remaining q3v..q5v unused -> but we loaded 12 floats for 2 rows (6 floats). Trim:
  (void)q3v; (void)q4v; (void)q5v;

  float h0[12], h1[12];
  {
    float g6a[6], g6b[6];
    #pragma unroll
    for (int e=0;e<6;e++){
      float a0 = fmaf(xa0,w1[e*3+0], fmaf(xa1,w1[e*3+1], fmaf(xa2,w1[e*3+2], b1[e])));
      float a1v= fmaf(xb0,w1[e*3+0], fmaf(xb1,w1[e*3+1], fmaf(xb2,w1[e*3+2], b1[e])));
      g6a[e]=fmaxf(fmaf(a0,sA0,hA0),0.f);
      g6b[e]=fmaxf(fmaf(a1v,sA1,hA1),0.f);
    }
    #pragma unroll
    for (int d=0;d<12;d++){
      float z0=b2[d], z1=b2[d];
      #pragma unroll
      for (int e=0;e<6;e++){ z0=fmaf(g6a[e],w2[d*6+e],z0); z1=fmaf(g6b[e],w2[d*6+e],z1); }
      h0[d]=fmaxf(fmaf(z0,sB0,hB0),0.f);
      h1[d]=fmaxf(fmaf(z1,sB1,hB1),0.f);
    }
  }

  float X0[12], X1[12];
  #pragma unroll
  for (int d=0; d<12; d++){
    float z0=b3[d], z1=b3[d];
    #pragma unroll
    for (int e=0;e<12;e++){ z0=fmaf(h0[e],w3[d*12+e],z0); z1=fmaf(h1[e],w3[d*12+e],z1); }
    X0[d]=sigmoidf_(z0); X1[d]=sigmoidf_(z1);
  }

  const float* UW[4]  = {u1w,u2w,u3w,u4w};
  const float* UBv[4] = {u1b,u2b,u3b,u4b};
  const float cf[4] = {
    wr1[0]*ps1[0]*ph1[0]*(1.f/128.f),
    wr2[0]*ps2[0]*ph2[0]*(1.f/128.f),
    wr3[0]*ps3[0]*ph3[0]*(1.f/128.f),
    wr4[0]*ps4[0]*ph4[0]*(1.f/128.f)
  };

  const int g = lane>>4;
  int kc = lane & 15; if (kc>11) kc=11;

  #pragma unroll
  for (int l=0;l<4;l++){
    const float* uw = UW[l];
    const float* ub = UBv[l];
    float U0[12], U1[12];
    #pragma unroll
    for (int d=0;d<12;d++){
      float z0=ub[d], z1=ub[d];
      #pragma unroll
      for (int e=0;e<12;e++){ z0=fmaf(X0[e],uw[d*12+e],z0); z1=fmaf(X1[e],uw[d*12+e],z1); }
      U0[d]=fmaxf(z0,0.f); U1[d]=fmaxf(z1,0.f);
    }
    float q0=0.f, q1=0.f;
    #pragma unroll
    for (int e=0;e<12;e++){ q0=fmaf(X0[e],X0[e],q0); q1=fmaf(X1[e],X1[e],q1); }

    // stage U (f32, 24 floats contiguous per lane, 16B aligned)
    float4* uwr = (float4*)(Us + r0*12);
    uwr[0]=make_float4(U0[0],U0[1],U0[2],U0[3]);
    uwr[1]=make_float4(U0[4],U0[5],U0[6],U0[7]);
    uwr[2]=make_float4(U0[8],U0[9],U0[10],U0[11]);
    uwr[3]=make_float4(U1[0],U1[1],U1[2],U1[3]);
    uwr[4]=make_float4(U1[4],U1[5],U1[6],U1[7]);
    uwr[5]=make_float4(U1[8],U1[9],U1[10],U1[11]);
    // stage X (f16, 24 halves = 48B contiguous per lane, 16B aligned)
    __half2 hp[12];
    #pragma unroll
    for (int i=0;i<6;i++) hp[i]   = __floats2half2_rn(X0[2*i],X0[2*i+1]);
    #pragma unroll
    for (int i=0;i<6;i++) hp[6+i] = __floats2half2_rn(X1[2*i],X1[2*i+1]);
    {
      const uint4* hpv = (const uint4*)hp;
      uint4* xw = (uint4*)(Xs + r0*12);
      xw[0]=hpv[0]; xw[1]=hpv[1]; xw[2]=hpv[2];
    }
    // wave-coherent LDS: in-order DS per wave + compiler lgkmcnt; no barrier.

    // partial M[kc][d] over this lane's 32-row chunk; rotation de-conflicts banks
    float mp[12];
    #pragma unroll
    for (int d=0;d<12;d++) mp[d]=0.f;
    #pragma unroll
    for (int i=0;i<32;i++){
      const int n = (g<<5) + ((i+g)&31);
      const float xv = __half2float(Xs[n*12 + kc]);
      const float4* up = (const float4*)(Us + n*12);
      float4 u0=up[0], u1=up[1], u2=up[2];
      mp[0]=fmaf(xv,u0.x,mp[0]); mp[1]=fmaf(xv,u0.y,mp[1]); mp[2]=fmaf(xv,u0.z,mp[2]); mp[3]=fmaf(xv,u0.w,mp[3]);
      mp[4]=fmaf(xv,u1.x,mp[4]); mp[5]=fmaf(xv,u1.y,mp[5]); mp[6]=fmaf(xv,u1.z,mp[6]); mp[7]=fmaf(xv,u1.w,mp[7]);
      mp[8]=fmaf(xv,u2.x,mp[8]); mp[9]=fmaf(xv,u2.y,mp[9]); mp[10]=fmaf(xv,u2.z,mp[10]); mp[11]=fmaf(xv,u2.w,mp[11]);
    }
    #pragma unroll
    for (int d=0;d<12;d++) mp[d] += __shfl_xor(mp[d], 16, 64);
    #pragma unroll
    for (int d=0;d<12;d++) mp[d] += __shfl_xor(mp[d], 32, 64);

    // Y = X @ M ; M[k][d] lives in lane k's mp[d] -> broadcast via readlane (SGPR operand)
    float Y0[12], Y1[12];
    #pragma unroll
    for (int d=0;d<12;d++){ Y0[d]=0.f; Y1[d]=0.f; }
    #pragma unroll
    for (int k=0;k<12;k++){
      const float xa = X0[k], xb = X1[k];
      #pragma unroll
      for (int d=0;d<12;d++){
        const float m = __int_as_float(__builtin_amdgcn_readlane(__float_as_int(mp[d]), k));
        Y0[d]=fmaf(xa,m,Y0[d]); Y1[d]=fmaf(xb,m,Y1[d]);
      }
    }
    const float coef = cf[l];
    #pragma unroll
    for (int d=0;d<12;d++){
      X0[d] = coef*(Y0[d] - q0*U0[d]);
      X1[d] = coef*(Y1[d] - q1*U1[d]);
    }
  }

  // fc4 (12->6), write a4, bn4 stats (block-reduced, 8 shadow copies)
  float z0[6], z1[6];
  float s0=0.f,sq0=0.f,s1=0.f,sq1=0.f;
  #pragma unroll
  for (int e=0;e<6;e++){
    float a0=b4[e], a1v=b4[e];
    #pragma unroll
    for (int d=0;d<12;d++){ a0=fmaf(X0[d],w4[e*12+d],a0); a1v=fmaf(X1[d],w4[e*12+d],a1v); }
    z0[e]=a0; z1[e]=a1v;
    s0+=a0; sq0=fmaf(a0,a0,sq0); s1+=a1v; sq1=fmaf(a1v,a1v,sq1);
  }
  float4* aw = (float4*)(a4 + ((size_t)b*128 + r0)*6);
  aw[0]=make_float4(z0[0],z0[1],z0[2],z0[3]);
  aw[1]=make_float4(z0[4],z0[5],z1[0],z1[1]);
  aw[2]=make_float4(z1[2],z1[3],z1[4],z1[5]);

  lds[wave][r0]=s0; lds[wave][r1]=s1;
  lds[wave][128+r0]=sq0; lds[wave][128+r1]=sq1;
  __syncthreads();
  const int t = threadIdx.x;
  const int c = (blockIdx.x & 7)*256;
  if (t < 128){
    float tot = lds[0][t]+lds[1][t]+lds[2][t]+lds[3][t];
    atomicAdd(&st[512 + c + t], tot);
  } else {
    const int tt = t-128;
    float tot = lds[0][128+tt]+lds[1][128+tt]+lds[2][128+tt]+lds[3][128+tt];
    atomicAdd(&st[512 + c + 128 + tt], tot);
  }
}

// bn4+relu + fc5+relu + fc6/fc7 + max over N + fc8 + sigmoid.
__global__ __launch_bounds__(256) void k4(
  const float* __restrict__ a4, const float* __restrict__ g4, const float* __restrict__ bb4,
  const float* __restrict__ w5, const float* __restrict__ b5,
  const float* __restrict__ w6, const float* __restrict__ b6,
  const float* __restrict__ w7, const float* __restrict__ b7,
  const float* __restrict__ w8, const float* __restrict__ b8,
  const float* __restrict__ st, float* __restrict__ out)
{
  const int wave = threadIdx.x>>6, lane = threadIdx.x&63;
  const int b = blockIdx.x*4 + wave;
  const int r0 = lane*2, r1 = r0+1;
  float ss0=0.f, qq0=0.f, ss1=0.f, qq1=0.f;
  #pragma unroll
  for (int cc=0;cc<8;cc++){
    ss0 += st[512+cc*256+r0];     qq0 += st[512+cc*256+128+r0];
    ss1 += st[512+cc*256+r1];     qq1 += st[512+cc*256+128+r1];
  }
  const float inv = 1.f/(BB*6);
  const float mean0 = ss0*inv, var0 = qq0*inv - mean0*mean0;
  const float sc0 = g4[r0]*rsqrtf(var0+EPS), sh0 = bb4[r0]-mean0*sc0;
  const float mean1 = ss1*inv, var1 = qq1*inv - mean1*mean1;
  const float sc1 = g4[r1]*rsqrtf(var1+EPS), sh1 = bb4[r1]-mean1*sc1;

  const float4* ar = (const float4*)(a4 + ((size_t)b*128 + r0)*6);
  float4 p0=ar[0], p1=ar[1], p2=ar[2];
  float h0[6] = {p0.x,p0.y,p0.z,p0.w,p1.x,p1.y};
  float h1[6] = {p1.z,p1.w,p2.x,p2.y,p2.z,p2.w};
  #pragma unroll
  for (int e=0;e<6;e++){
    h0[e]=fmaxf(fmaf(h0[e],sc0,sh0),0.f);
    h1[e]=fmaxf(fmaf(h1[e],sc1,sh1),0.f);
  }
  float m[3];
  {
    float h5a[3], h5b[3];
    #pragma unroll
    for (int f=0;f<3;f++){
      float za=b5[f], zb=b5[f];
      #pragma unroll
      for (int e=0;e<6;e++){ za=fmaf(h0[e],w5[f*6+e],za); zb=fmaf(h1[e],w5[f*6+e],zb); }
      h5a[f]=fmaxf(za,0.f); h5b[f]=fmaxf(zb,0.f);
    }
    float ca=b6[0], cb=b6[0];
    float g0a=b7[0], g0b=b7[0], g1a=b7[1], g1b=b7[1];
    #pragma unroll
    for (int f=0;f<3;f++){
      ca=fmaf(h5a[f],w6[f],ca);   cb=fmaf(h5b[f],w6[f],cb);
      g0a=fmaf(h5a[f],w7[f],g0a); g0b=fmaf(h5b[f],w7[f],g0b);
      g1a=fmaf(h5a[f],w7[3+f],g1a); g1b=fmaf(h5b[f],w7[3+f],g1b);
    }
    m[0]=fmaxf(ca,cb); m[1]=fmaxf(g0a,g0b); m[2]=fmaxf(g1a,g1b);
  }
  #pragma unroll
  for (int off=32; off>0; off>>=1){
    m[0]=fmaxf(m[0], __shfl_xor(m[0],off,64));
    m[1]=fmaxf(m[1], __shfl_xor(m[1],off,64));
    m[2]=fmaxf(m[2], __shfl_xor(m[2],off,64));
  }
  if (lane==0){
    float z = b8[0] + m[0]*w8[0] + m[1]*w8[1] + m[2]*w8[2];
    out[b]=sigmoidf_(z);
  }
}

extern "C" void kernel_launch(void* const* d_in, const int* in_sizes, int n_in,
                              void* d_out, int out_size, void* d_ws, size_t ws_size,
                              hipStream_t stream){
  const float* x   = (const float*)d_in[0];
  const float* f1w = (const float*)d_in[1];
  const float* f1b = (const float*)d_in[2];
  const float* g1  = (const float*)d_in[3];
  const float* bb1 = (const float*)d_in[4];
  const float* f2w = (const float*)d_in[5];
  const float* f2b = (const float*)d_in[6];
  const float* g2  = (const float*)d_in[7];
  const float* bb2 = (const float*)d_in[8];
  const float* f3w = (const float*)d_in[9];
  const float* f3b = (const float*)d_in[10];
  const float* u1w = (const float*)d_in[11];
  const float* u1b = (const float*)d_in[12];
  const float* ps1 = (const float*)d_in[13];
  const float* ph1 = (const float*)d_in[14];
  const float* wr1 = (const float*)d_in[15];
  const float* u2w = (const float*)d_in[16];
  const float* u2b = (const float*)d_in[17];
  const float* ps2 = (const float*)d_in[18];
  const float* ph2 = (const float*)d_in[19];
  const float* wr2 = (const float*)d_in[20];
  const float* u3w = (const float*)d_in[21];
  const float* u3b = (const float*)d_in[22];
  const float* ps3 = (const float*)d_in[23];
  const float* ph3 = (const float*)d_in[24];
  const float* wr3 = (const float*)d_in[25];
  const float* u4w = (const float*)d_in[26];
  const float* u4b = (const float*)d_in[27];
  const float* ps4 = (const float*)d_in[28];
  const float* ph4 = (const float*)d_in[29];
  const float* wr4 = (const float*)d_in[30];
  const float* f4w = (const float*)d_in[31];
  const float* f4b = (const float*)d_in[32];
  const float* g4  = (const float*)d_in[33];
  const float* bb4 = (const float*)d_in[34];
  const float* f5w = (const float*)d_in[35];
  const float* f5b = (const float*)d_in[36];
  const float* f6w = (const float*)d_in[37];
  const float* f6b = (const float*)d_in[38];
  const float* f7w = (const float*)d_in[39];
  const float* f7b = (const float*)d_in[40];
  const float* f8w = (const float*)d_in[41];
  const float* f8b = (const float*)d_in[42];

  float* wsf = (float*)d_ws;
  float* st  = wsf;
  float* a4  = wsf + A4_OFF;
  float* out = (float*)d_out;

  hipMemsetAsync(st, 0, ST_FLOATS*sizeof(float), stream);
  k1<<<dim3(128), dim3(256), 0, stream>>>(x, f1w, f1b, st);
  k2<<<dim3(128), dim3(256), 0, stream>>>(x, f1w, f1b, g1, bb1, f2w, f2b, st);
  k3<<<dim3(1024), dim3(256), 0, stream>>>(x, f1w, f1b, g1, bb1, f2w, f2b, g2, bb2,
      f3w, f3b,
      u1w,u1b,ps1,ph1,wr1, u2w,u2b,ps2,ph2,wr2,
      u3w,u3b,ps3,ph3,wr3, u4w,u4b,ps4,ph4,wr4,
      f4w, f4b, a4, st);
  k4<<<dim3(1024), dim3(256), 0, stream>>>(a4, g4, bb4, f5w, f5b,
      f6w, f6b, f7w, f7b, f8w, f8b, st, out);
}